// Round 3
// baseline (121.060 us; speedup 1.0000x reference)
//
#include <hip/hip_runtime.h>
#include <stdint.h>

#define N_ROWS 8192
#define FEAT   256
#define RB     256                    // rows per unit block
#define NB     (N_ROWS / RB)          // 32 row-blocks
#define NPAIR  (NB * (NB + 1) / 2)    // 528 (a<=b) pairs
#define NSLOT  (2 * NB)               // 64 partial slots per row
#define CT     64                     // cols staged per chunk (32 KB)

typedef __bf16 bf16x8 __attribute__((ext_vector_type(8)));
typedef float  f32x4  __attribute__((ext_vector_type(4)));

__device__ __forceinline__ unsigned short f2bf(float x) {
    union { float f; uint32_t u; } v; v.f = x;
    uint32_t u = v.u;
    return (unsigned short)((u + 0x7FFFu + ((u >> 16) & 1u)) >> 16);
}

__device__ __forceinline__ void gld16(const unsigned short* g, unsigned short* l) {
    // direct global->LDS, 16 B per lane; LDS dest must be wave-linear (it is)
    __builtin_amdgcn_global_load_lds((__attribute__((address_space(1))) void*)g,
                                     (__attribute__((address_space(3))) void*)l,
                                     16, 0, 0);
}

// ---- Kernel 1: normalize rows -> bf16 copy (16B-chunk XOR-swizzled rows);
//      fused positive-pair dot. 4 waves/block = 4 consecutive rows.
__global__ void knorm(const float* __restrict__ feat,
                      unsigned short* __restrict__ fb,
                      float* __restrict__ pos) {
    __shared__ float ex[4][FEAT];
    int wave = threadIdx.x >> 6;
    int lane = threadIdx.x & 63;
    int row  = blockIdx.x * 4 + wave;
    float4 v = ((const float4*)(feat + row * FEAT))[lane];
    float ss = v.x*v.x + v.y*v.y + v.z*v.z + v.w*v.w;
    #pragma unroll
    for (int off = 1; off < 64; off <<= 1) ss += __shfl_xor(ss, off);
    float inv = 1.0f / fmaxf(sqrtf(ss), 1e-12f);
    float4 o; o.x = v.x*inv; o.y = v.y*inv; o.z = v.z*inv; o.w = v.w*inv;
    ushort4 b;
    b.x = f2bf(o.x); b.y = f2bf(o.y); b.z = f2bf(o.z); b.w = f2bf(o.w);
    // row layout: 32 chunks of 16B; chunk c stored at position c ^ (row&7).
    int sidx = (((lane >> 1) ^ (row & 7)) << 1) | (lane & 1);
    ((ushort4*)(fb + row * FEAT))[sidx] = b;
    ((float4*)ex[wave])[lane] = o;
    __syncthreads();
    float4 p = ((float4*)ex[wave ^ 1])[lane];
    float d = o.x*p.x + o.y*p.y + o.z*p.z + o.w*p.w;
    #pragma unroll
    for (int off = 1; off < 64; off <<= 1) d += __shfl_xor(d, off);
    if (lane == 0) pos[row] = d;
}

// ---- Kernel 2: SYMMETRIC tiled f@f^T with fused fixed-max exp-sum --------
// Each block = one (a<=b) 256-row-block pair x one 128-col half. exp(s) of
// each computed element is credited to BOTH its row sum (rows of a) and its
// column sum (rows of b) -> each similarity computed once: MFMA, exp and
// LDS traffic all ~halve vs the full-matrix version.
// partial slots: row-sums of unit (a,b,h) -> slot 2b+h; col-sums -> slot 2a
// (the two h-units write disjoint 128-row halves of b, so they share slot
// 2a). Diagonal (a==a) masks j==i via the cg==rb tile check and skips
// col-sums; its h==0 block zero-fills the never-written slots {2j+1: j<a}.
__global__ __launch_bounds__(256, 1)
void kmain(const unsigned short* __restrict__ fb, float* __restrict__ partial) {
    __shared__ unsigned short bufA[CT * FEAT];   // 32 KB
    __shared__ unsigned short bufB[CT * FEAT];   // 32 KB
    __shared__ float colred[4][128];             //  2 KB
    const int t    = threadIdx.x;
    const int lane = t & 63;
    const int wave = t >> 6;          // 0..3
    const int quad = lane >> 4;       // 0..3
    const int l15  = lane & 15;

    // decode blockIdx.x -> (a, b, h): pair index row-major over a<=b
    const int pair = blockIdx.x >> 1;
    const int h    = blockIdx.x & 1;
    int a = 0, rem = pair;
    while (rem >= NB - a) { rem -= NB - a; ++a; }
    const int b = a + rem;
    const bool isdiag = (a == b);

    const int rw    = a * RB + wave * 64;        // this wave's 64 A-rows
    const int cbase = b * RB + h * 128;          // this block's 128 B-cols
    const float Kc = 20.60992915555662f;         // log2(e)/0.07

#define STAGE(DST, CC0) do {                                                  \
    const unsigned short* sp_ = fb + (size_t)(cbase + (CC0)) * FEAT + t * 8;  \
    unsigned short* dp_ = (DST) + t * 8;                                      \
    _Pragma("unroll")                                                         \
    for (int i_ = 0; i_ < 8; ++i_)                                            \
        gld16(sp_ + i_ * 2048, dp_ + i_ * 2048);                              \
} while (0)

    STAGE(bufA, 0);    // chunk 0 in flight while we load A fragments

    // A fragments: 64 rows x K=256 resident in registers (128 VGPRs)
    bf16x8 af[4][8];
    #pragma unroll
    for (int rf = 0; rf < 4; ++rf)
        #pragma unroll
        for (int ks = 0; ks < 8; ++ks) {
            int row = rw + rf * 16 + l15;
            int ch  = (ks * 4 + quad) ^ (row & 7);   // undo layout swizzle
            af[rf][ks] = *(const bf16x8*)(fb + row * FEAT + ch * 8);
        }

    float lsum[4][4] = {{0.f,0.f,0.f,0.f},{0.f,0.f,0.f,0.f},
                        {0.f,0.f,0.f,0.f},{0.f,0.f,0.f,0.f}};
    float cs[8] = {0.f,0.f,0.f,0.f,0.f,0.f,0.f,0.f};

#define EPI(AC, RF, G) do {                                                   \
    const int rb_ = rw + (RF) * 16;                                           \
    const bool dg_ = (cg == rb_);    /* only possible on diagonal units */    \
    _Pragma("unroll")                                                         \
    for (int r_ = 0; r_ < 4; ++r_) {                                          \
        float e_ = __builtin_amdgcn_exp2f(fmaf((AC)[r_], Kc, -Kc));           \
        if (dg_ && (rb_ + quad * 4 + r_ == C)) e_ = 0.f;  /* mask j == i */   \
        lsum[(RF)][r_] += e_;                                                 \
        cs[(G)] += e_;                                                        \
    }                                                                         \
} while (0)

#define COMPUTE(BS, CC0, CS0) do {                                            \
    _Pragma("unroll")                                                         \
    for (int g = 0; g < 4; ++g) {                                             \
        const int cg = cbase + (CC0) + g * 16;                                \
        const int C  = cg + l15;                                              \
        f32x4 ac0 = {0.f,0.f,0.f,0.f};                                        \
        f32x4 ac1 = {0.f,0.f,0.f,0.f};                                        \
        f32x4 ac2 = {0.f,0.f,0.f,0.f};                                        \
        f32x4 ac3 = {0.f,0.f,0.f,0.f};                                        \
        _Pragma("unroll")                                                     \
        for (int ks = 0; ks < 8; ++ks) {                                      \
            bf16x8 bv = *(const bf16x8*)((BS) + (g * 16 + l15) * FEAT         \
                                        + (((ks * 4 + quad) ^ (l15 & 7)) * 8)); \
            ac0 = __builtin_amdgcn_mfma_f32_16x16x32_bf16(af[0][ks], bv, ac0, 0, 0, 0); \
            ac1 = __builtin_amdgcn_mfma_f32_16x16x32_bf16(af[1][ks], bv, ac1, 0, 0, 0); \
            ac2 = __builtin_amdgcn_mfma_f32_16x16x32_bf16(af[2][ks], bv, ac2, 0, 0, 0); \
            ac3 = __builtin_amdgcn_mfma_f32_16x16x32_bf16(af[3][ks], bv, ac3, 0, 0, 0); \
        }                                                                     \
        EPI(ac0, 0, (CS0) + g); EPI(ac1, 1, (CS0) + g);                       \
        EPI(ac2, 2, (CS0) + g); EPI(ac3, 3, (CS0) + g);                       \
    }                                                                         \
} while (0)

    asm volatile("s_waitcnt vmcnt(0)" ::: "memory");
    __builtin_amdgcn_s_barrier();
    STAGE(bufB, CT);                 // prefetch chunk 1
    COMPUTE(bufA, 0, 0);             // compute chunk 0
    asm volatile("s_waitcnt vmcnt(0)" ::: "memory");
    __builtin_amdgcn_s_barrier();
    COMPUTE(bufB, CT, 4);            // compute chunk 1

    // ---- row sums -> partial[2b+h][rows of a] ----------------------------
    const int rslot = 2 * b + h;
    #pragma unroll
    for (int rf = 0; rf < 4; ++rf)
        #pragma unroll
        for (int r = 0; r < 4; ++r) {
            float v = lsum[rf][r];
            v += __shfl_xor(v, 1);
            v += __shfl_xor(v, 2);
            v += __shfl_xor(v, 4);
            v += __shfl_xor(v, 8);
            lsum[rf][r] = v;
        }
    if (l15 == 0) {
        #pragma unroll
        for (int rf = 0; rf < 4; ++rf)
            #pragma unroll
            for (int r = 0; r < 4; ++r) {
                int row = rw + rf * 16 + quad * 4 + r;
                partial[rslot * N_ROWS + row] = lsum[rf][r];
            }
    }

    // ---- col sums -> partial[2a][rows of b, half h] ----------------------
    #pragma unroll
    for (int g = 0; g < 8; ++g) {
        float v = cs[g];
        v += __shfl_xor(v, 16);      // sum across quads
        v += __shfl_xor(v, 32);
        if (lane < 16) colred[wave][g * 16 + l15] = v;
    }
    __syncthreads();
    if (!isdiag && t < 128) {
        float s = colred[0][t] + colred[1][t] + colred[2][t] + colred[3][t];
        partial[(2 * a) * N_ROWS + b * RB + h * 128 + t] = s;
    }
    // diagonal h==0 block zero-fills the slots no unit writes for block a
    if (isdiag && h == 0) {
        for (int j = 0; j < a; ++j)
            partial[(2 * j + 1) * N_ROWS + a * RB + t] = 0.f;
    }
#undef STAGE
#undef COMPUTE
#undef EPI
}

// ---- Kernel 3: per-row loss + block tree-reduce --------------------------
__global__ void kreduce(const float* __restrict__ partial,
                        const float* __restrict__ pos,
                        float* __restrict__ bsum) {
    __shared__ float red[4];
    int row  = blockIdx.x * 256 + threadIdx.x;
    int wave = threadIdx.x >> 6;
    int lane = threadIdx.x & 63;
    float L = 0.f;
    #pragma unroll
    for (int p = 0; p < NSLOT; ++p) L += partial[p * N_ROWS + row];
    const float invT = 14.285714285714286f;
    // loss_i = (1 - pos_i)/T + ln2 * log2(L)   (v_log_f32 is log2)
    float loss = invT * (1.0f - pos[row])
               + 0.6931471805599453f * __builtin_amdgcn_logf(L);
    #pragma unroll
    for (int off = 1; off < 64; off <<= 1) loss += __shfl_xor(loss, off);
    if (lane == 0) red[wave] = loss;
    __syncthreads();
    if (threadIdx.x == 0)
        bsum[blockIdx.x] = red[0] + red[1] + red[2] + red[3];
}

// ---- Kernel 4: final 32 -> 1 ---------------------------------------------
__global__ void kfinal(const float* __restrict__ bsum, float* __restrict__ out) {
    int lane = threadIdx.x;
    float v = (lane < 32) ? bsum[lane] : 0.f;
    #pragma unroll
    for (int off = 1; off < 32; off <<= 1) v += __shfl_xor(v, off);
    if (lane == 0) out[0] = v * (1.0f / 8192.0f);
}

extern "C" void kernel_launch(void* const* d_in, const int* in_sizes, int n_in,
                              void* d_out, int out_size, void* d_ws, size_t ws_size,
                              hipStream_t stream) {
    const float* feat = (const float*)d_in[0];
    float* out = (float*)d_out;
    char* ws = (char*)d_ws;
    unsigned short* fb      = (unsigned short*)ws;                    // 4 MB bf16 (swizzled rows)
    float*          partial = (float*)(ws + (4u << 20));              // 2 MB (64 slots x 8192)
    float*          pos     = (float*)(ws + (6u << 20));              // 32 KB
    float*          bsum    = (float*)(ws + (6u << 20) + (1u << 15));

    knorm<<<N_ROWS / 4, 256, 0, stream>>>(feat, fb, pos);
    kmain<<<NPAIR * 2, 256, 0, stream>>>(fb, partial);
    kreduce<<<N_ROWS / 256, 256, 0, stream>>>(partial, pos, bsum);
    kfinal<<<1, 64, 0, stream>>>(bsum, out);
}

// Round 4
// 100.899 us; speedup vs baseline: 1.1998x; 1.1998x over previous
//
#include <hip/hip_runtime.h>
#include <stdint.h>

#define N_ROWS 8192
#define FEAT   256
#define YSPLIT 16
#define CPB    (N_ROWS / YSPLIT)   // 512 cols per kmain block
#define CT     64                  // cols staged per chunk (32 KB)

typedef __bf16 bf16x8 __attribute__((ext_vector_type(8)));
typedef float  f32x4  __attribute__((ext_vector_type(4)));

__device__ __forceinline__ unsigned short f2bf(float x) {
    union { float f; uint32_t u; } v; v.f = x;
    uint32_t u = v.u;
    return (unsigned short)((u + 0x7FFFu + ((u >> 16) & 1u)) >> 16);
}

__device__ __forceinline__ void gld16(const unsigned short* g, unsigned short* l) {
    __builtin_amdgcn_global_load_lds((__attribute__((address_space(1))) void*)g,
                                     (__attribute__((address_space(3))) void*)l,
                                     16, 0, 0);
}

// ---- Kernel 1: normalize rows -> bf16 copy (16B-chunk XOR-swizzled rows);
//      fused positive-pair dot. 4 waves/block = 4 consecutive rows.
__global__ void knorm(const float* __restrict__ feat,
                      unsigned short* __restrict__ fb,
                      float* __restrict__ pos) {
    __shared__ float ex[4][FEAT];
    int wave = threadIdx.x >> 6;
    int lane = threadIdx.x & 63;
    int row  = blockIdx.x * 4 + wave;
    float4 v = ((const float4*)(feat + row * FEAT))[lane];
    float ss = v.x*v.x + v.y*v.y + v.z*v.z + v.w*v.w;
    #pragma unroll
    for (int off = 1; off < 64; off <<= 1) ss += __shfl_xor(ss, off);
    float inv = 1.0f / fmaxf(sqrtf(ss), 1e-12f);
    float4 o; o.x = v.x*inv; o.y = v.y*inv; o.z = v.z*inv; o.w = v.w*inv;
    ushort4 b;
    b.x = f2bf(o.x); b.y = f2bf(o.y); b.z = f2bf(o.z); b.w = f2bf(o.w);
    int sidx = (((lane >> 1) ^ (row & 7)) << 1) | (lane & 1);
    ((ushort4*)(fb + row * FEAT))[sidx] = b;
    ((float4*)ex[wave])[lane] = o;
    __syncthreads();
    float4 p = ((float4*)ex[wave ^ 1])[lane];
    float d = o.x*p.x + o.y*p.y + o.z*p.z + o.w*p.w;
    #pragma unroll
    for (int off = 1; off < 64; off <<= 1) d += __shfl_xor(d, off);
    if (lane == 0) pos[row] = d;
}

// ---- Kernel 2: tiled f@f^T with fused fixed-max exp-sum ------------------
// Round-2 structure (full matrix, grid (32,16), 4 waves x 64 rows, dbuf LDS
// via global_load_lds). NEW: two accumulator banks + the exp-epilogue of
// MFMA-group g-1 hand-interleaved into the MFMA issue of group g, 2 elems
// per K-step, so each wave's stream mixes MFMA/DS/VALU/trans at fine grain
// (pipes overlap regardless of wave phase alignment). setprio(1) during
// the mixed groups biases CU arbitration toward MFMA-feeding waves.
__global__ __launch_bounds__(256, 1)
void kmain(const unsigned short* __restrict__ fb, float* __restrict__ partial) {
    __shared__ unsigned short bufA[CT * FEAT];   // 32 KB
    __shared__ unsigned short bufB[CT * FEAT];   // 32 KB
    const int t    = threadIdx.x;
    const int lane = t & 63;
    const int wave = t >> 6;          // 0..3
    const int quad = lane >> 4;       // 0..3
    const int l15  = lane & 15;
    const int rw    = blockIdx.x * 256 + wave * 64;
    const int cbase = blockIdx.y * CPB;
    const float Kc = 20.60992915555662f;          // log2(e)/0.07

#define STAGE(DST, CC0) do {                                                  \
    const unsigned short* sp_ = fb + (size_t)(cbase + (CC0)) * FEAT + t * 8;  \
    unsigned short* dp_ = (DST) + t * 8;                                      \
    _Pragma("unroll")                                                         \
    for (int i_ = 0; i_ < 8; ++i_)                                            \
        gld16(sp_ + i_ * 2048, dp_ + i_ * 2048);                              \
} while (0)

    STAGE(bufA, 0);    // chunk 0 in flight while we load A fragments

    // A fragments: 64 rows x K=256 resident in registers (128 VGPRs)
    bf16x8 af[4][8];
    #pragma unroll
    for (int rf = 0; rf < 4; ++rf)
        #pragma unroll
        for (int ks = 0; ks < 8; ++ks) {
            int row = rw + rf * 16 + l15;
            int ch  = (ks * 4 + quad) ^ (row & 7);   // undo layout swizzle
            af[rf][ks] = *(const bf16x8*)(fb + row * FEAT + ch * 8);
        }

    float lsum[4][4] = {{0.f,0.f,0.f,0.f},{0.f,0.f,0.f,0.f},
                        {0.f,0.f,0.f,0.f},{0.f,0.f,0.f,0.f}};

    // one K-step of group G: ds_read B-frag + 4 MFMAs into bank W0..W3
#define KSTEP(BS, G, KS, W0, W1, W2, W3) do {                                 \
    bf16x8 bv_ = *(const bf16x8*)((BS) + ((G) * 16 + l15) * FEAT              \
                                  + ((((KS) * 4 + quad) ^ (l15 & 7)) * 8));   \
    W0 = __builtin_amdgcn_mfma_f32_16x16x32_bf16(af[0][KS], bv_, W0, 0, 0, 0);\
    W1 = __builtin_amdgcn_mfma_f32_16x16x32_bf16(af[1][KS], bv_, W1, 0, 0, 0);\
    W2 = __builtin_amdgcn_mfma_f32_16x16x32_bf16(af[2][KS], bv_, W2, 0, 0, 0);\
    W3 = __builtin_amdgcn_mfma_f32_16x16x32_bf16(af[3][KS], bv_, W3, 0, 0, 0);\
} while (0)

    // one epilogue element (group GP, row-frag RF, elem RI) from acc AC
#define EPI_ONE(C0, GP, RF, RI, AC) do {                                      \
    const int cgp_ = (C0) + (GP) * 16;                                        \
    const bool dgp_ = (cgp_ == rw + (RF) * 16);  /* wave-uniform tile-diag */ \
    float e_ = __builtin_amdgcn_exp2f(fmaf((AC)[RI], Kc, -Kc));               \
    if (dgp_ && (rw + (RF) * 16 + quad * 4 + (RI) == cgp_ + l15)) e_ = 0.f;   \
    lsum[RF][RI] += e_;                                                       \
} while (0)

    // group with no interleaved epilogue (first group of a chunk)
#define GRP0(BS, C0, G, W0, W1, W2, W3) do {                                  \
    W0 = (f32x4){0.f,0.f,0.f,0.f}; W1 = (f32x4){0.f,0.f,0.f,0.f};             \
    W2 = (f32x4){0.f,0.f,0.f,0.f}; W3 = (f32x4){0.f,0.f,0.f,0.f};             \
    __builtin_amdgcn_s_setprio(1);                                            \
    KSTEP(BS, G, 0, W0, W1, W2, W3);                                          \
    KSTEP(BS, G, 1, W0, W1, W2, W3);                                          \
    KSTEP(BS, G, 2, W0, W1, W2, W3);                                          \
    KSTEP(BS, G, 3, W0, W1, W2, W3);                                          \
    KSTEP(BS, G, 4, W0, W1, W2, W3);                                          \
    KSTEP(BS, G, 5, W0, W1, W2, W3);                                          \
    KSTEP(BS, G, 6, W0, W1, W2, W3);                                          \
    KSTEP(BS, G, 7, W0, W1, W2, W3);                                          \
    __builtin_amdgcn_s_setprio(0);                                            \
} while (0)

    // group G MFMA into bank W*, interleaved with group GP epilogue from R*
#define GRP(BS, C0, G, W0, W1, W2, W3, GP, R0, R1, R2, R3) do {               \
    W0 = (f32x4){0.f,0.f,0.f,0.f}; W1 = (f32x4){0.f,0.f,0.f,0.f};             \
    W2 = (f32x4){0.f,0.f,0.f,0.f}; W3 = (f32x4){0.f,0.f,0.f,0.f};             \
    __builtin_amdgcn_s_setprio(1);                                            \
    KSTEP(BS, G, 0, W0, W1, W2, W3);                                          \
    EPI_ONE(C0, GP, 0, 0, R0); EPI_ONE(C0, GP, 0, 1, R0);                     \
    KSTEP(BS, G, 1, W0, W1, W2, W3);                                          \
    EPI_ONE(C0, GP, 0, 2, R0); EPI_ONE(C0, GP, 0, 3, R0);                     \
    KSTEP(BS, G, 2, W0, W1, W2, W3);                                          \
    EPI_ONE(C0, GP, 1, 0, R1); EPI_ONE(C0, GP, 1, 1, R1);                     \
    KSTEP(BS, G, 3, W0, W1, W2, W3);                                          \
    EPI_ONE(C0, GP, 1, 2, R1); EPI_ONE(C0, GP, 1, 3, R1);                     \
    KSTEP(BS, G, 4, W0, W1, W2, W3);                                          \
    EPI_ONE(C0, GP, 2, 0, R2); EPI_ONE(C0, GP, 2, 1, R2);                     \
    KSTEP(BS, G, 5, W0, W1, W2, W3);                                          \
    EPI_ONE(C0, GP, 2, 2, R2); EPI_ONE(C0, GP, 2, 3, R2);                     \
    KSTEP(BS, G, 6, W0, W1, W2, W3);                                          \
    EPI_ONE(C0, GP, 3, 0, R3); EPI_ONE(C0, GP, 3, 1, R3);                     \
    KSTEP(BS, G, 7, W0, W1, W2, W3);                                          \
    EPI_ONE(C0, GP, 3, 2, R3); EPI_ONE(C0, GP, 3, 3, R3);                     \
    __builtin_amdgcn_s_setprio(0);                                            \
} while (0)

#define EPI_TAIL(C0, GP, R0, R1, R2, R3) do {                                 \
    EPI_ONE(C0, GP, 0, 0, R0); EPI_ONE(C0, GP, 0, 1, R0);                     \
    EPI_ONE(C0, GP, 0, 2, R0); EPI_ONE(C0, GP, 0, 3, R0);                     \
    EPI_ONE(C0, GP, 1, 0, R1); EPI_ONE(C0, GP, 1, 1, R1);                     \
    EPI_ONE(C0, GP, 1, 2, R1); EPI_ONE(C0, GP, 1, 3, R1);                     \
    EPI_ONE(C0, GP, 2, 0, R2); EPI_ONE(C0, GP, 2, 1, R2);                     \
    EPI_ONE(C0, GP, 2, 2, R2); EPI_ONE(C0, GP, 2, 3, R2);                     \
    EPI_ONE(C0, GP, 3, 0, R3); EPI_ONE(C0, GP, 3, 1, R3);                     \
    EPI_ONE(C0, GP, 3, 2, R3); EPI_ONE(C0, GP, 3, 3, R3);                     \
} while (0)

    // full 64-col chunk: 4 groups, 2 acc banks, EPI(g-1) inside MFMA(g)
#define COMPUTE_PIPE(BS, CC0) do {                                            \
    const int c0_ = cbase + (CC0);                                            \
    f32x4 A0, A1, A2, A3, B0, B1, B2, B3;                                     \
    GRP0(BS, c0_, 0, A0, A1, A2, A3);                                         \
    GRP (BS, c0_, 1, B0, B1, B2, B3, 0, A0, A1, A2, A3);                      \
    GRP (BS, c0_, 2, A0, A1, A2, A3, 1, B0, B1, B2, B3);                      \
    GRP (BS, c0_, 3, B0, B1, B2, B3, 2, A0, A1, A2, A3);                      \
    EPI_TAIL(c0_, 3, B0, B1, B2, B3);                                         \
} while (0)

    asm volatile("s_waitcnt vmcnt(0)" ::: "memory");
    __builtin_amdgcn_s_barrier();
    for (int ct2 = 0; ct2 < CPB / CT; ct2 += 2) {
        // phase A: prefetch next chunk into bufB, compute from bufA
        STAGE(bufB, (ct2 + 1) * CT);
        COMPUTE_PIPE(bufA, ct2 * CT);
        asm volatile("s_waitcnt vmcnt(0)" ::: "memory");
        __builtin_amdgcn_s_barrier();
        // phase B: prefetch next chunk into bufA, compute from bufB
        if (ct2 + 2 < CPB / CT) STAGE(bufA, (ct2 + 2) * CT);
        COMPUTE_PIPE(bufB, (ct2 + 1) * CT);
        asm volatile("s_waitcnt vmcnt(0)" ::: "memory");
        __builtin_amdgcn_s_barrier();
    }

    #pragma unroll
    for (int rf = 0; rf < 4; ++rf)
        #pragma unroll
        for (int r = 0; r < 4; ++r) {
            float v = lsum[rf][r];
            v += __shfl_xor(v, 1);
            v += __shfl_xor(v, 2);
            v += __shfl_xor(v, 4);
            v += __shfl_xor(v, 8);
            lsum[rf][r] = v;
        }
    if (l15 == 0) {
        #pragma unroll
        for (int rf = 0; rf < 4; ++rf)
            #pragma unroll
            for (int r = 0; r < 4; ++r) {
                int row = rw + rf * 16 + quad * 4 + r;
                partial[blockIdx.y * N_ROWS + row] = lsum[rf][r];
            }
    }
#undef STAGE
#undef KSTEP
#undef EPI_ONE
#undef GRP0
#undef GRP
#undef EPI_TAIL
#undef COMPUTE_PIPE
}

// ---- Kernel 3: per-row loss + block tree-reduce --------------------------
__global__ void kreduce(const float* __restrict__ partial,
                        const float* __restrict__ pos,
                        float* __restrict__ bsum) {
    __shared__ float red[4];
    int row  = blockIdx.x * 256 + threadIdx.x;
    int wave = threadIdx.x >> 6;
    int lane = threadIdx.x & 63;
    float L = 0.f;
    #pragma unroll
    for (int p = 0; p < YSPLIT; ++p) L += partial[p * N_ROWS + row];
    const float invT = 14.285714285714286f;
    float loss = invT * (1.0f - pos[row])
               + 0.6931471805599453f * __builtin_amdgcn_logf(L);
    #pragma unroll
    for (int off = 1; off < 64; off <<= 1) loss += __shfl_xor(loss, off);
    if (lane == 0) red[wave] = loss;
    __syncthreads();
    if (threadIdx.x == 0)
        bsum[blockIdx.x] = red[0] + red[1] + red[2] + red[3];
}

// ---- Kernel 4: final 32 -> 1 ---------------------------------------------
__global__ void kfinal(const float* __restrict__ bsum, float* __restrict__ out) {
    int lane = threadIdx.x;
    float v = (lane < 32) ? bsum[lane] : 0.f;
    #pragma unroll
    for (int off = 1; off < 32; off <<= 1) v += __shfl_xor(v, off);
    if (lane == 0) out[0] = v * (1.0f / 8192.0f);
}

extern "C" void kernel_launch(void* const* d_in, const int* in_sizes, int n_in,
                              void* d_out, int out_size, void* d_ws, size_t ws_size,
                              hipStream_t stream) {
    const float* feat = (const float*)d_in[0];
    float* out = (float*)d_out;
    char* ws = (char*)d_ws;
    unsigned short* fb      = (unsigned short*)ws;                    // 4 MB bf16 (swizzled rows)
    float*          partial = (float*)(ws + (4u << 20));              // 512 KB (16 slots)
    float*          pos     = (float*)(ws + (4u << 20) + (1u << 19)); // 32 KB
    float*          bsum    = (float*)(ws + (4u << 20) + (1u << 19) + (1u << 15));

    knorm<<<N_ROWS / 4, 256, 0, stream>>>(feat, fb, pos);
    kmain<<<dim3(32, YSPLIT), 256, 0, stream>>>(fb, partial);
    kreduce<<<N_ROWS / 256, 256, 0, stream>>>(partial, pos, bsum);
    kfinal<<<1, 64, 0, stream>>>(bsum, out);
}